// Round 18
// baseline (470.784 us; speedup 1.0000x reference)
//
#include <hip/hip_runtime.h>
#include <math.h>

#define L_LEN 4096
#define DEV __device__ __forceinline__

typedef __attribute__((ext_vector_type(8))) _Float16 f16x8;
typedef __attribute__((ext_vector_type(4))) float   f32x4;

DEV float fast_rcp(float d) {
    float r = __int_as_float(0x7EF311C3 - __float_as_int(d));
    r = r * (2.f - d * r);
    r = r * (2.f - d * r);
    return r;
}
DEV float silu_f(float x) {
    const float y = exp2f(-1.44269504f * fmaxf(x, -80.f));
    return x * fast_rcp(1.f + y);
}
DEV float sigm_f(float x) {
    const float y = exp2f(-1.44269504f * fmaxf(x, -80.f));
    return fast_rcp(1.f + y);
}

DEV void gload16(const void* g, void* l) {
    __builtin_amdgcn_global_load_lds(
        (const __attribute__((address_space(1))) void*)g,
        (__attribute__((address_space(3))) void*)l, 16, 0, 0);
}

// ============================================================================
// conv1: CIN=1, K=5, pad=2 (fp32 direct; writes fp16 channels-last)
// ============================================================================
__global__ __launch_bounds__(256) void conv1_k(
    const float* __restrict__ x, const float* __restrict__ W,
    const float* __restrict__ bias, const float* __restrict__ bnp,
    _Float16* __restrict__ out)
{
    __shared__ float sw[64 * 5];
    __shared__ float ssc[64], ssh[64];
    const int tid = threadIdx.x;
    if (tid < 64) {
        float g = bnp[tid], be = bnp[64 + tid], mn = bnp[128 + tid], vr = bnp[192 + tid];
        float sc = g * rsqrtf(vr + 1e-5f);
        ssc[tid] = sc;
        ssh[tid] = fmaf(bias[tid] - mn, sc, be);
    }
    for (int i = tid; i < 320; i += 256) sw[i] = W[i];
    __syncthreads();

    const int b = blockIdx.y;
    const int l = blockIdx.x * 64 + (tid >> 2);
    const int cq = (tid & 3) * 16;

    float win[5];
#pragma unroll
    for (int k = 0; k < 5; ++k) {
        int ix = l + k - 2;
        win[k] = (ix >= 0 && ix < L_LEN) ? x[(size_t)b * L_LEN + ix] : 0.f;
    }
    __align__(16) _Float16 vv[16];
#pragma unroll
    for (int j = 0; j < 16; ++j) {
        const int co = cq + j;
        float z = 0.f;
#pragma unroll
        for (int k = 0; k < 5; ++k) z = fmaf(sw[co * 5 + k], win[k], z);
        z = fmaf(z, ssc[co], ssh[co]);
        vv[j] = (_Float16)silu_f(z);
    }
    const size_t o = ((size_t)b * L_LEN + l) * 64 + cq;
    *(int4*)(out + o)     = *(const int4*)(vv);
    *(int4*)(out + o + 8) = *(const int4*)(vv + 8);
}

// ============================================================================
// merged weight prep -> fragment-order fp16: [s][t][n][lane][8] per layer
// ============================================================================
struct PrepArgs {
    const float* W[6];
    _Float16*    wf[6];
    int cin[6], cout[6], kk[6];
    int cum[7];
};

__global__ void prep_all_k(PrepArgs a)
{
    const int id0 = blockIdx.x * 256 + threadIdx.x;
    if (id0 >= a.cum[6]) return;
    int sg = 0;
    while (sg < 5 && id0 >= a.cum[sg + 1]) ++sg;
    const int id   = id0 - a.cum[sg];
    const int CIN  = a.cin[sg], COUT = a.cout[sg], K = a.kk[sg];
    const int NTILE = COUT / 16;
    const int lane = id & 63;
    int r = id >> 6;
    const int n = r % NTILE; r /= NTILE;
    const int t = r % K;
    const int s = r / K;

    const int co  = n * 16 + (lane & 15);
    const int cib = s * 32 + (lane >> 4) * 8;
    const float* W = a.W[sg];
    __align__(16) _Float16 v8[8];
#pragma unroll
    for (int j = 0; j < 8; ++j)
        v8[j] = (_Float16)W[((size_t)co * CIN + cib + j) * K + t];
    *(int4*)(a.wf[sg] + (size_t)id * 8) = *(const int4*)v8;
}

// ============================================================================
// BN fold prep: scsh[layer] = [sc (COUT) | sh (COUT)] computed once
// ============================================================================
struct BnArgs {
    const float* bias[6];
    const float* bnp[6];
    float*       scsh[6];
    int cout[6];
    int cum[7];
};

__global__ void bn_prep_k(BnArgs a)
{
    const int t = blockIdx.x * 256 + threadIdx.x;
    if (t >= a.cum[6]) return;
    int sg = 0;
    while (sg < 5 && t >= a.cum[sg + 1]) ++sg;
    const int co = t - a.cum[sg];
    const int C  = a.cout[sg];
    const float g = a.bnp[sg][co], be = a.bnp[sg][C + co];
    const float mn = a.bnp[sg][2 * C + co], vr = a.bnp[sg][3 * C + co];
    const float sc = g * rsqrtf(vr + 1e-5f);
    a.scsh[sg][co]     = sc;
    a.scsh[sg][C + co] = fmaf(a.bias[sg][co] - mn, sc, be);
}

// ============================================================================
// MFMA fp16 implicit-GEMM conv — full-CIN single stage, barrier-free phases.
// Block: 256 thr = 4 waves (2 wl x 2 wc); tile = 128 l x COUT.
// A: staged once into LDS (row stride CIN*2+16 B). B: fragment-order weights,
// 2-phase-ahead register prefetch. Swapped MFMA operands: D[co][l].
// NEW (R17): epilogue aux/gate loads HOISTED into the prologue so their
// latency hides under staging-drain + the 12-phase MFMA loop.
// Epilogue:
//   MODE 0/1: z -> LDS [128][COUT+4] (b64 scatter) -> coalesced int4 sweep.
//   MODE 3  : direct-from-acc pooled silu(z+aux_reg) -> shfl_xor reduce
//             -> pf[2][COUT] -> 1 atomic/channel.
// ============================================================================
template <int CIN, int COUT, int K, int DIL, int MODE>
__launch_bounds__(256, 2) __global__ void conv_mfma_k(
    const _Float16* __restrict__ in, const _Float16* __restrict__ wf,
    const float* __restrict__ scsh,
    const _Float16* __restrict__ aux, _Float16* __restrict__ out,
    float* __restrict__ gsum, const float* __restrict__ zpage)
{
    constexpr int SL    = CIN / 32;
    constexpr int P     = SL * K;
    constexpr int PADR  = ((K - 1) / 2) * DIL;
    constexpr int LWIN  = 128 + (K - 1) * DIL;
    constexpr int NT    = COUT / 32;
    constexpr int NTILE = COUT / 16;
    constexpr int SLOTS = CIN / 8 + 1;
    constexpr int RSTR  = SLOTS * 16;
    constexpr int CH_IN = LWIN * SLOTS;
    constexpr int STGB  = LWIN * RSTR;
    constexpr int ESTR  = COUT + 4;
    constexpr int EPIB  = 128 * ESTR * 2;
    constexpr int SMEMB = (MODE == 3) ? STGB : ((STGB > EPIB) ? STGB : EPIB);
    constexpr int CO8   = COUT / 8;
    constexpr int LG    = (CO8 == 16) ? 4 : (CO8 == 8) ? 3 : 2;
    constexpr int RPI   = 64 / CO8;

    __shared__ __align__(16) char smem[SMEMB];
    __shared__ float pf[(MODE == 3) ? 2 : 1][COUT];

    const int tid   = threadIdx.x;
    const int lane  = tid & 63;
    const int w     = tid >> 6;
    const int wl    = w >> 1;
    const int wc    = w & 1;
    const int b     = blockIdx.z;
    const int l0    = blockIdx.x * 128;
    const int lan15 = lane & 15;
    const int kgB   = (lane >> 4) * 16;

    const size_t bL = (size_t)b * L_LEN;

    auto loadB = [&](int p, f16x8 (&dst)[NT]) {
        const _Float16* bbase = wf + (size_t)p * (NTILE * 512);
#pragma unroll
        for (int nt = 0; nt < NT; ++nt) {
            const int ntg = wc * NT + nt;
            dst[nt] = *(const f16x8*)(bbase + ntg * 512 + lane * 8);
        }
    };

    f32x4 acc[4][NT];
#pragma unroll
    for (int mt = 0; mt < 4; ++mt)
#pragma unroll
        for (int nt = 0; nt < NT; ++nt) acc[mt][nt] = (f32x4){0.f, 0.f, 0.f, 0.f};

    f16x8 brbuf[2][NT];

    // ---- stage the ENTIRE input window once (lane-linear dst) ----
    for (int c = tid; c < CH_IN; c += 256) {
        const int row  = c / SLOTS;
        const int slot = c - row * SLOTS;
        const int gl   = l0 - PADR + row;
        const bool ok  = (slot < SLOTS - 1) & (gl >= 0) & (gl < L_LEN);
        const _Float16* s0 = in + ((bL + gl) * CIN + slot * 8);
        const void* src = ok ? (const void*)s0 : (const void*)zpage;
        gload16(src, smem + (size_t)c * 16);
    }

    // ---- HOISTED epilogue loads: latency hides under drain + MFMA loop ----
    int2 a16[(MODE == 3) ? 4 : 1][(MODE == 3) ? NT : 1];
    int4 gx[(MODE == 1) ? (CO8 / 2) : 1];
    if constexpr (MODE == 3) {
#pragma unroll
        for (int mt = 0; mt < 4; ++mt)
#pragma unroll
            for (int nt = 0; nt < NT; ++nt) {
                const int co0 = (wc * NT + nt) * 16 + (lane >> 4) * 4;
                const int l = wl * 64 + mt * 16 + lan15;
                a16[mt][nt] = *(const int2*)(aux + (bL + l0 + l) * COUT + co0);
            }
    } else if constexpr (MODE == 1) {
        const int cos = (lane & (CO8 - 1)) * 8;
#pragma unroll
        for (int s2 = 0; s2 < CO8 / 2; ++s2) {
            const int l = w * 32 + s2 * RPI + (lane >> LG);
            gx[s2] = *(const int4*)(aux + (bL + l0 + l) * COUT + cos);
        }
    }

    loadB(0, brbuf[0]);
    if (P > 1) loadB(1, brbuf[1]);
    asm volatile("s_waitcnt vmcnt(0)" ::: "memory");
    __builtin_amdgcn_sched_barrier(0);
    __syncthreads();

    // ---- barrier-free static phase loop ----
#pragma unroll
    for (int pp = 0; pp < P; ++pp) {
        const int ss = pp / K;
        const int tt = pp % K;
#pragma unroll
        for (int mt = 0; mt < 4; ++mt) {
            const int row = wl * 64 + mt * 16 + lan15 + tt * DIL;
            const f16x8 a = *(const f16x8*)(smem + row * RSTR + ss * 64 + kgB);
#pragma unroll
            for (int nt = 0; nt < NT; ++nt)
                acc[mt][nt] = __builtin_amdgcn_mfma_f32_16x16x32_f16(brbuf[pp & 1][nt], a, acc[mt][nt], 0, 0, 0);
        }
        if (pp + 2 < P) loadB(pp + 2, brbuf[pp & 1]);
    }

    // ---------------- epilogue ----------------
    if constexpr (MODE == 3) {
        // direct-from-acc pooled reduce; aux already in registers
#pragma unroll
        for (int nt = 0; nt < NT; ++nt) {
            const int co0 = (wc * NT + nt) * 16 + (lane >> 4) * 4;
            const float4 s4 = *(const float4*)&scsh[co0];
            const float4 h4 = *(const float4*)&scsh[COUT + co0];
            const float sc[4] = {s4.x, s4.y, s4.z, s4.w};
            const float sh[4] = {h4.x, h4.y, h4.z, h4.w};

            float ps[4] = {0.f, 0.f, 0.f, 0.f};
#pragma unroll
            for (int mt = 0; mt < 4; ++mt) {
                _Float16 a4[4];
                *(int2*)a4 = a16[mt][nt];
#pragma unroll
                for (int r = 0; r < 4; ++r)
                    ps[r] += silu_f(fmaf(acc[mt][nt][r], sc[r], sh[r]) + (float)a4[r]);
            }
#pragma unroll
            for (int r = 0; r < 4; ++r) {
                ps[r] += __shfl_xor(ps[r], 1, 64);
                ps[r] += __shfl_xor(ps[r], 2, 64);
                ps[r] += __shfl_xor(ps[r], 4, 64);
                ps[r] += __shfl_xor(ps[r], 8, 64);
            }
            if (lan15 == 0) {
#pragma unroll
                for (int r = 0; r < 4; ++r)
                    pf[wl][co0 + r] = ps[r];
            }
        }
        __syncthreads();
        if (tid < COUT)
            atomicAdd(&gsum[b * COUT + tid], pf[0][tid] + pf[1][tid]);
    } else {
        // z -> LDS (b64 scatter) -> coalesced sweep
        __syncthreads();
        _Float16* zl = (_Float16*)smem;
#pragma unroll
        for (int nt = 0; nt < NT; ++nt) {
            const int co0 = (wc * NT + nt) * 16 + (lane >> 4) * 4;
            const float4 s4 = *(const float4*)&scsh[co0];
            const float4 h4 = *(const float4*)&scsh[COUT + co0];
            const float sc[4] = {s4.x, s4.y, s4.z, s4.w};
            const float sh[4] = {h4.x, h4.y, h4.z, h4.w};
#pragma unroll
            for (int mt = 0; mt < 4; ++mt) {
                const int l_loc = wl * 64 + mt * 16 + lan15;
                __align__(8) _Float16 o4[4];
#pragma unroll
                for (int r = 0; r < 4; ++r)
                    o4[r] = (_Float16)fmaf(acc[mt][nt][r], sc[r], sh[r]);
                *(int2*)&zl[l_loc * ESTR + co0] = *(const int2*)o4;
            }
        }
        __syncthreads();

        const int co = (lane & (CO8 - 1)) * 8;
#pragma unroll
        for (int s2 = 0; s2 < CO8 / 2; ++s2) {
            const int l = w * 32 + s2 * RPI + (lane >> LG);
            _Float16 z8[8];
            *(int4*)z8 = *(const int4*)&zl[l * ESTR + co];
            const size_t gidx = (bL + l0 + l) * COUT + co;
            __align__(16) _Float16 o8[8];
            if constexpr (MODE == 0) {
#pragma unroll
                for (int j = 0; j < 8; ++j) o8[j] = (_Float16)silu_f((float)z8[j]);
            } else {
                _Float16 g8[8];
                *(int4*)g8 = gx[s2];
#pragma unroll
                for (int j = 0; j < 8; ++j) o8[j] = (_Float16)((float)g8[j] * sigm_f((float)z8[j]));
            }
            *(int4*)(out + gidx) = *(const int4*)o8;
        }
    }
}

// ============================================================================
// 4-qubit statevector circuit helpers
// ============================================================================
template <int BW> DEV void g_ry(float (&re)[16], float (&im)[16], float t) {
    float s, c; sincosf(0.5f * t, &s, &c);
#pragma unroll
    for (int i = 0; i < 16; ++i)
        if (!(i & BW)) {
            const int j = i | BW;
            float r0 = re[i], q0 = im[i], r1 = re[j], q1 = im[j];
            re[i] = c * r0 - s * r1; im[i] = c * q0 - s * q1;
            re[j] = s * r0 + c * r1; im[j] = s * q0 + c * q1;
        }
}
template <int BW> DEV void g_rz(float (&re)[16], float (&im)[16], float t) {
    float s, c; sincosf(0.5f * t, &s, &c);
#pragma unroll
    for (int i = 0; i < 16; ++i) {
        float r = re[i], q = im[i];
        if (i & BW) { re[i] = r * c - q * s; im[i] = q * c + r * s; }
        else        { re[i] = r * c + q * s; im[i] = q * c - r * s; }
    }
}
template <int BC, int BT> DEV void g_cnot(float (&re)[16], float (&im)[16]) {
#pragma unroll
    for (int i = 0; i < 16; ++i)
        if ((i & BC) && !(i & BT)) {
            const int j = i | BT;
            float r = re[i]; re[i] = re[j]; re[j] = r;
            float q = im[i]; im[i] = im[j]; im[j] = q;
        }
}

// ============================================================================
// merged quantum + FC head: one block (64 thr) per batch row
// ============================================================================
__global__ __launch_bounds__(64) void qhead_k(
    const float* __restrict__ gsum, const float* __restrict__ Wfm,
    const float* __restrict__ bfm, const float* __restrict__ qw,
    const float* __restrict__ Wf1, const float* __restrict__ bf1, const float* __restrict__ bnf1,
    const float* __restrict__ Wf2, const float* __restrict__ bf2, const float* __restrict__ bnf2,
    const float* __restrict__ Wf3, const float* __restrict__ bf3,
    float* __restrict__ out)
{
    const int b = blockIdx.x, t = threadIdx.x;
    const float inv = 1.f / (float)L_LEN;

    float part[4];
    {
        const float gv0 = gsum[b * 128 + t] * inv;
        const float gv1 = gsum[b * 128 + 64 + t] * inv;
#pragma unroll
        for (int j = 0; j < 4; ++j)
            part[j] = gv0 * Wfm[j * 128 + t] + gv1 * Wfm[j * 128 + 64 + t];
    }
#pragma unroll
    for (int j = 0; j < 4; ++j) {
#pragma unroll
        for (int m = 1; m < 64; m <<= 1)
            part[j] += __shfl_xor(part[j], m, 64);
        part[j] += bfm[j];
    }

    float re[16], im[16];
#pragma unroll
    for (int i = 0; i < 16; ++i) { re[i] = 0.f; im[i] = 0.f; }
    re[0] = 1.f;
    g_ry<8>(re, im, part[0]); g_ry<4>(re, im, part[1]); g_ry<2>(re, im, part[2]); g_ry<1>(re, im, part[3]);
    g_rz<8>(re, im, qw[0]);  g_ry<8>(re, im, qw[1]);
    g_rz<4>(re, im, qw[2]);  g_ry<4>(re, im, qw[3]);
    g_rz<2>(re, im, qw[4]);  g_ry<2>(re, im, qw[5]);
    g_rz<1>(re, im, qw[6]);  g_ry<1>(re, im, qw[7]);
    g_cnot<8, 4>(re, im); g_cnot<4, 2>(re, im); g_cnot<2, 1>(re, im);
    g_rz<8>(re, im, qw[8]);  g_ry<8>(re, im, qw[9]);
    g_rz<4>(re, im, qw[10]); g_ry<4>(re, im, qw[11]);
    g_rz<2>(re, im, qw[12]); g_ry<2>(re, im, qw[13]);
    g_rz<1>(re, im, qw[14]); g_ry<1>(re, im, qw[15]);

    float pr[16];
#pragma unroll
    for (int i = 0; i < 16; ++i) pr[i] = re[i] * re[i] + im[i] * im[i];
    float q[4];
#pragma unroll
    for (int w = 0; w < 4; ++w) {
        const int bw = 8 >> w;
        float e = 0.f;
#pragma unroll
        for (int i = 0; i < 16; ++i) e += (i & bw) ? -pr[i] : pr[i];
        q[w] = e;
    }

    __shared__ float x1[64], x2[32];
    {
        float a = bf1[t];
#pragma unroll
        for (int k = 0; k < 4; ++k) a = fmaf(q[k], Wf1[t * 4 + k], a);
        const float sc = bnf1[t] / sqrtf(bnf1[192 + t] + 1e-5f);
        const float z  = (a - bnf1[128 + t]) * sc + bnf1[64 + t];
        x1[t] = silu_f(z);
    }
    __syncthreads();
    if (t < 32) {
        float a = bf2[t];
        for (int k = 0; k < 64; ++k) a = fmaf(x1[k], Wf2[t * 64 + k], a);
        const float sc = bnf2[t] / sqrtf(bnf2[96 + t] + 1e-5f);
        const float z  = (a - bnf2[64 + t]) * sc + bnf2[32 + t];
        x2[t] = silu_f(z);
    }
    __syncthreads();
    if (t == 0) {
        float a = bf3[0];
        for (int k = 0; k < 32; ++k) a = fmaf(x2[k], Wf3[k], a);
        out[b] = a;
    }
}

// ============================================================================
extern "C" void kernel_launch(void* const* d_in, const int* in_sizes, int n_in,
                              void* d_out, int out_size, void* d_ws, size_t ws_size,
                              hipStream_t stream)
{
    (void)n_in; (void)out_size;
    const float* x    = (const float*)d_in[0];
    const float* W1   = (const float*)d_in[1];
    const float* b1   = (const float*)d_in[2];
    const float* bn1  = (const float*)d_in[3];
    const float* Wa1  = (const float*)d_in[4];
    const float* ba1  = (const float*)d_in[5];
    const float* bna1 = (const float*)d_in[6];
    const float* Wa2  = (const float*)d_in[7];
    const float* ba2  = (const float*)d_in[8];
    const float* bna2 = (const float*)d_in[9];
    const float* Wd1  = (const float*)d_in[10];
    const float* bdd1 = (const float*)d_in[11];
    const float* bnd1 = (const float*)d_in[12];
    const float* Wd2  = (const float*)d_in[13];
    const float* bdd2 = (const float*)d_in[14];
    const float* bnd2 = (const float*)d_in[15];
    const float* Wr1  = (const float*)d_in[16];
    const float* br1  = (const float*)d_in[17];
    const float* bnr1 = (const float*)d_in[18];
    const float* Wr2  = (const float*)d_in[19];
    const float* br2  = (const float*)d_in[20];
    const float* bnr2 = (const float*)d_in[21];
    const float* Wfm  = (const float*)d_in[22];
    const float* bfm  = (const float*)d_in[23];
    const float* qw   = (const float*)d_in[24];
    const float* Wf1  = (const float*)d_in[25];
    const float* bf1  = (const float*)d_in[26];
    const float* bnf1 = (const float*)d_in[27];
    const float* Wf2  = (const float*)d_in[28];
    const float* bf2  = (const float*)d_in[29];
    const float* bnf2 = (const float*)d_in[30];
    const float* Wf3  = (const float*)d_in[31];
    const float* bf3  = (const float*)d_in[32];

    const int B = in_sizes[0] / L_LEN;  // 128

    char* base = (char*)d_ws;
    size_t off = 0;
    auto alloc = [&](size_t bytes) -> char* {
        off = (off + 255) & ~(size_t)255;
        char* p = base + off;
        off += bytes;
        return p;
    };

    float* gbuf  = (float*)alloc((size_t)B * 128 * 4);
    float* zpage = (float*)alloc(256);

    auto wfrag = [&](int cin, int cout, int k) -> _Float16* {
        return (_Float16*)alloc((size_t)k * cout * cin * 2);
    };
    _Float16* wa1f = wfrag(64, 32, 7);
    _Float16* wa2f = wfrag(32, 64, 7);
    _Float16* wd1f = wfrag(64, 128, 3);
    _Float16* wd2f = wfrag(128, 128, 3);
    _Float16* wr1f = wfrag(128, 128, 3);
    _Float16* wr2f = wfrag(128, 128, 3);

    auto scshb = [&](int cout) -> float* { return (float*)alloc((size_t)cout * 2 * 4); };
    float* sA1 = scshb(32);
    float* sA2 = scshb(64);
    float* sD1 = scshb(128);
    float* sD2 = scshb(128);
    float* sR1 = scshb(128);
    float* sR2 = scshb(128);

    const size_t fixed = (off + 255) & ~(size_t)255;
    const size_t PS = (size_t)2 * L_LEN * 256;
    size_t avail = (ws_size > fixed + 4096) ? ws_size - fixed - 4096 : 0;
    int chunk = B;
    while (chunk > 1 && (size_t)chunk * PS > avail) chunk >>= 1;

    auto aplane = [&](int C, int c) -> _Float16* {
        return (_Float16*)alloc((size_t)c * L_LEN * C * 2);
    };
    _Float16* h0 = aplane(64,  chunk);   // region A
    _Float16* a1 = aplane(32,  chunk);   // region B
    (void)     aplane(32,  chunk);       // region E (spacer for d2 overlap)
    _Float16* d1 = aplane(128, chunk);   // region C (also r1)
    _Float16* d2 = h0;                   // d2 aliases A∪B∪E
    _Float16* r1 = d1;

    PrepArgs pa;
    pa.W[0] = Wa1; pa.wf[0] = wa1f; pa.cin[0] = 64;  pa.cout[0] = 32;  pa.kk[0] = 7;
    pa.W[1] = Wa2; pa.wf[1] = wa2f; pa.cin[1] = 32;  pa.cout[1] = 64;  pa.kk[1] = 7;
    pa.W[2] = Wd1; pa.wf[2] = wd1f; pa.cin[2] = 64;  pa.cout[2] = 128; pa.kk[2] = 3;
    pa.W[3] = Wd2; pa.wf[3] = wd2f; pa.cin[3] = 128; pa.cout[3] = 128; pa.kk[3] = 3;
    pa.W[4] = Wr1; pa.wf[4] = wr1f; pa.cin[4] = 128; pa.cout[4] = 128; pa.kk[4] = 3;
    pa.W[5] = Wr2; pa.wf[5] = wr2f; pa.cin[5] = 128; pa.cout[5] = 128; pa.kk[5] = 3;
    pa.cum[0] = 0;
    for (int i = 0; i < 6; ++i)
        pa.cum[i + 1] = pa.cum[i] + (pa.cin[i] / 32) * pa.kk[i] * (pa.cout[i] / 16) * 64;
    prep_all_k<<<dim3((pa.cum[6] + 255) / 256), dim3(256), 0, stream>>>(pa);

    BnArgs ba;
    ba.bias[0] = ba1;  ba.bnp[0] = bna1; ba.scsh[0] = sA1; ba.cout[0] = 32;
    ba.bias[1] = ba2;  ba.bnp[1] = bna2; ba.scsh[1] = sA2; ba.cout[1] = 64;
    ba.bias[2] = bdd1; ba.bnp[2] = bnd1; ba.scsh[2] = sD1; ba.cout[2] = 128;
    ba.bias[3] = bdd2; ba.bnp[3] = bnd2; ba.scsh[3] = sD2; ba.cout[3] = 128;
    ba.bias[4] = br1;  ba.bnp[4] = bnr1; ba.scsh[4] = sR1; ba.cout[4] = 128;
    ba.bias[5] = br2;  ba.bnp[5] = bnr2; ba.scsh[5] = sR2; ba.cout[5] = 128;
    ba.cum[0] = 0;
    for (int i = 0; i < 6; ++i) ba.cum[i + 1] = ba.cum[i] + ba.cout[i];
    bn_prep_k<<<dim3((ba.cum[6] + 255) / 256), dim3(256), 0, stream>>>(ba);

    hipMemsetAsync(gbuf, 0, (size_t)B * 128 * sizeof(float), stream);
    hipMemsetAsync(zpage, 0, 256, stream);

    const dim3 blk(256);
    for (int sft = 0; sft < B; sft += chunk) {
        const int c = (chunk < B - sft) ? chunk : (B - sft);
        const dim3 cg(L_LEN / 128, 1, c);
        conv1_k<<<dim3(64, c), blk, 0, stream>>>(x + (size_t)sft * L_LEN, W1, b1, bn1, h0);
        conv_mfma_k<64, 32, 7, 1, 0><<<cg, blk, 0, stream>>>(h0, wa1f, sA1, nullptr, a1, nullptr, zpage);
        conv_mfma_k<32, 64, 7, 1, 1><<<cg, blk, 0, stream>>>(a1, wa2f, sA2, h0, h0, nullptr, zpage);
        conv_mfma_k<64, 128, 3, 2, 0><<<cg, blk, 0, stream>>>(h0, wd1f, sD1, nullptr, d1, nullptr, zpage);
        conv_mfma_k<128, 128, 3, 4, 0><<<cg, blk, 0, stream>>>(d1, wd2f, sD2, nullptr, d2, nullptr, zpage);
        conv_mfma_k<128, 128, 3, 1, 0><<<cg, blk, 0, stream>>>(d2, wr1f, sR1, nullptr, r1, nullptr, zpage);
        conv_mfma_k<128, 128, 3, 1, 3><<<cg, blk, 0, stream>>>(r1, wr2f, sR2, d2, nullptr, gbuf + (size_t)sft * 128, zpage);
    }

    qhead_k<<<dim3(B), dim3(64), 0, stream>>>(gbuf, Wfm, bfm, qw,
                                              Wf1, bf1, bnf1, Wf2, bf2, bnf2, Wf3, bf3,
                                              (float*)d_out);
}

// Round 19
// 452.486 us; speedup vs baseline: 1.0404x; 1.0404x over previous
//
#include <hip/hip_runtime.h>
#include <math.h>

#define L_LEN 4096
#define DEV __device__ __forceinline__

typedef __attribute__((ext_vector_type(8))) _Float16 f16x8;
typedef __attribute__((ext_vector_type(4))) float   f32x4;

// fast reciprocal: bit-trick seed + 2 Newton steps (rel err ~1e-6)
DEV float fast_rcp(float d) {
    float r = __int_as_float(0x7EF311C3 - __float_as_int(d));
    r = r * (2.f - d * r);
    r = r * (2.f - d * r);
    return r;
}
// silu/sigmoid with a single transcendental (exp2); clamp keeps d finite
DEV float silu_f(float x) {
    const float y = exp2f(-1.44269504f * fmaxf(x, -80.f));
    return x * fast_rcp(1.f + y);
}
DEV float sigm_f(float x) {
    const float y = exp2f(-1.44269504f * fmaxf(x, -80.f));
    return fast_rcp(1.f + y);
}

DEV void gload16(const void* g, void* l) {
    __builtin_amdgcn_global_load_lds(
        (const __attribute__((address_space(1))) void*)g,
        (__attribute__((address_space(3))) void*)l, 16, 0, 0);
}

// ============================================================================
// conv1: CIN=1, K=5, pad=2 (fp32 direct; writes fp16 channels-last)
// ============================================================================
__global__ __launch_bounds__(256) void conv1_k(
    const float* __restrict__ x, const float* __restrict__ W,
    const float* __restrict__ bias, const float* __restrict__ bnp,
    _Float16* __restrict__ out)
{
    __shared__ float sw[64 * 5];
    __shared__ float ssc[64], ssh[64];
    const int tid = threadIdx.x;
    if (tid < 64) {
        float g = bnp[tid], be = bnp[64 + tid], mn = bnp[128 + tid], vr = bnp[192 + tid];
        float sc = g * rsqrtf(vr + 1e-5f);
        ssc[tid] = sc;
        ssh[tid] = fmaf(bias[tid] - mn, sc, be);
    }
    for (int i = tid; i < 320; i += 256) sw[i] = W[i];
    __syncthreads();

    const int b = blockIdx.y;
    const int l = blockIdx.x * 64 + (tid >> 2);
    const int cq = (tid & 3) * 16;

    float win[5];
#pragma unroll
    for (int k = 0; k < 5; ++k) {
        int ix = l + k - 2;
        win[k] = (ix >= 0 && ix < L_LEN) ? x[(size_t)b * L_LEN + ix] : 0.f;
    }
    __align__(16) _Float16 vv[16];
#pragma unroll
    for (int j = 0; j < 16; ++j) {
        const int co = cq + j;
        float z = 0.f;
#pragma unroll
        for (int k = 0; k < 5; ++k) z = fmaf(sw[co * 5 + k], win[k], z);
        z = fmaf(z, ssc[co], ssh[co]);
        vv[j] = (_Float16)silu_f(z);
    }
    const size_t o = ((size_t)b * L_LEN + l) * 64 + cq;
    *(int4*)(out + o)     = *(const int4*)(vv);
    *(int4*)(out + o + 8) = *(const int4*)(vv + 8);
}

// ============================================================================
// merged weight prep -> fragment-order fp16: [s][t][n][lane][8] per layer
// ============================================================================
struct PrepArgs {
    const float* W[6];
    _Float16*    wf[6];
    int cin[6], cout[6], kk[6];
    int cum[7];
};

__global__ void prep_all_k(PrepArgs a)
{
    const int id0 = blockIdx.x * 256 + threadIdx.x;
    if (id0 >= a.cum[6]) return;
    int sg = 0;
    while (sg < 5 && id0 >= a.cum[sg + 1]) ++sg;
    const int id   = id0 - a.cum[sg];
    const int CIN  = a.cin[sg], COUT = a.cout[sg], K = a.kk[sg];
    const int NTILE = COUT / 16;
    const int lane = id & 63;
    int r = id >> 6;
    const int n = r % NTILE; r /= NTILE;
    const int t = r % K;
    const int s = r / K;

    const int co  = n * 16 + (lane & 15);
    const int cib = s * 32 + (lane >> 4) * 8;
    const float* W = a.W[sg];
    __align__(16) _Float16 v8[8];
#pragma unroll
    for (int j = 0; j < 8; ++j)
        v8[j] = (_Float16)W[((size_t)co * CIN + cib + j) * K + t];
    *(int4*)(a.wf[sg] + (size_t)id * 8) = *(const int4*)v8;
}

// ============================================================================
// BN fold prep: scsh[layer] = [sc (COUT) | sh (COUT)] computed once
// ============================================================================
struct BnArgs {
    const float* bias[6];
    const float* bnp[6];
    float*       scsh[6];
    int cout[6];
    int cum[7];
};

__global__ void bn_prep_k(BnArgs a)
{
    const int t = blockIdx.x * 256 + threadIdx.x;
    if (t >= a.cum[6]) return;
    int sg = 0;
    while (sg < 5 && t >= a.cum[sg + 1]) ++sg;
    const int co = t - a.cum[sg];
    const int C  = a.cout[sg];
    const float g = a.bnp[sg][co], be = a.bnp[sg][C + co];
    const float mn = a.bnp[sg][2 * C + co], vr = a.bnp[sg][3 * C + co];
    const float sc = g * rsqrtf(vr + 1e-5f);
    a.scsh[sg][co]     = sc;
    a.scsh[sg][C + co] = fmaf(a.bias[sg][co] - mn, sc, be);
}

// ============================================================================
// MFMA fp16 implicit-GEMM conv — full-CIN single stage, barrier-free phases.
// Block: 256 thr = 4 waves (2 wl x 2 wc); tile = 128 l x COUT.  (R12-proven)
// A: whole input window staged once into LDS, row stride CIN*2+16 B.
// B: fragment-order weights, 2-phase-ahead register prefetch.
// MFMA operands SWAPPED: D[co][l] -> lane holds 4 consecutive co at one l.
// BN fold pre-computed (scsh); single-trans silu/sigmoid.
// Epilogue:
//   MODE 0/1: z -> LDS [128][COUT+4] (b64 scatter) -> coalesced int4 sweep.
//   MODE 3  : direct-from-acc pooled silu(z+aux) -> shfl_xor reduce
//             -> pf[2][COUT] -> 1 atomic/channel.
// ============================================================================
template <int CIN, int COUT, int K, int DIL, int MODE>
__launch_bounds__(256, 2) __global__ void conv_mfma_k(
    const _Float16* __restrict__ in, const _Float16* __restrict__ wf,
    const float* __restrict__ scsh,
    const _Float16* __restrict__ aux, _Float16* __restrict__ out,
    float* __restrict__ gsum, const float* __restrict__ zpage)
{
    constexpr int SL    = CIN / 32;
    constexpr int P     = SL * K;
    constexpr int PADR  = ((K - 1) / 2) * DIL;
    constexpr int LWIN  = 128 + (K - 1) * DIL;
    constexpr int NT    = COUT / 32;
    constexpr int NTILE = COUT / 16;
    constexpr int SLOTS = CIN / 8 + 1;          // 16B chunks per row (+1 pad)
    constexpr int RSTR  = SLOTS * 16;           // row stride bytes
    constexpr int CH_IN = LWIN * SLOTS;
    constexpr int STGB  = LWIN * RSTR;
    constexpr int ESTR  = COUT + 4;             // epilogue row stride (halves)
    constexpr int EPIB  = 128 * ESTR * 2;
    constexpr int SMEMB = (MODE == 3) ? STGB : ((STGB > EPIB) ? STGB : EPIB);

    __shared__ __align__(16) char smem[SMEMB];
    __shared__ float pf[(MODE == 3) ? 2 : 1][COUT];

    const int tid   = threadIdx.x;
    const int lane  = tid & 63;
    const int w     = tid >> 6;
    const int wl    = w >> 1;
    const int wc    = w & 1;
    const int b     = blockIdx.z;
    const int l0    = blockIdx.x * 128;
    const int lan15 = lane & 15;
    const int kgB   = (lane >> 4) * 16;

    const size_t bL = (size_t)b * L_LEN;

    auto loadB = [&](int p, f16x8 (&dst)[NT]) {
        const _Float16* bbase = wf + (size_t)p * (NTILE * 512);
#pragma unroll
        for (int nt = 0; nt < NT; ++nt) {
            const int ntg = wc * NT + nt;
            dst[nt] = *(const f16x8*)(bbase + ntg * 512 + lane * 8);
        }
    };

    f32x4 acc[4][NT];
#pragma unroll
    for (int mt = 0; mt < 4; ++mt)
#pragma unroll
        for (int nt = 0; nt < NT; ++nt) acc[mt][nt] = (f32x4){0.f, 0.f, 0.f, 0.f};

    f16x8 brbuf[2][NT];

    // ---- stage the ENTIRE input window once (lane-linear dst) ----
    for (int c = tid; c < CH_IN; c += 256) {
        const int row  = c / SLOTS;
        const int slot = c - row * SLOTS;
        const int gl   = l0 - PADR + row;
        const bool ok  = (slot < SLOTS - 1) & (gl >= 0) & (gl < L_LEN);
        const _Float16* s0 = in + ((bL + gl) * CIN + slot * 8);
        const void* src = ok ? (const void*)s0 : (const void*)zpage;
        gload16(src, smem + (size_t)c * 16);
    }
    loadB(0, brbuf[0]);
    if (P > 1) loadB(1, brbuf[1]);
    asm volatile("s_waitcnt vmcnt(0)" ::: "memory");
    __builtin_amdgcn_sched_barrier(0);
    __syncthreads();

    // ---- barrier-free static phase loop ----
#pragma unroll
    for (int pp = 0; pp < P; ++pp) {
        const int ss = pp / K;
        const int tt = pp % K;
#pragma unroll
        for (int mt = 0; mt < 4; ++mt) {
            const int row = wl * 64 + mt * 16 + lan15 + tt * DIL;
            const f16x8 a = *(const f16x8*)(smem + row * RSTR + ss * 64 + kgB);
#pragma unroll
            for (int nt = 0; nt < NT; ++nt) {
                // swapped operands: D rows = co, cols = l
                acc[mt][nt] = __builtin_amdgcn_mfma_f32_16x16x32_f16(brbuf[pp & 1][nt], a, acc[mt][nt], 0, 0, 0);
            }
        }
        if (pp + 2 < P) loadB(pp + 2, brbuf[pp & 1]);   // WAR-safe: after reads
    }

    // ---------------- epilogue ----------------
    if constexpr (MODE == 3) {
        // direct-from-acc pooled reduce (no global stores)
#pragma unroll
        for (int nt = 0; nt < NT; ++nt) {
            const int co0 = (wc * NT + nt) * 16 + (lane >> 4) * 4;
            const float4 s4 = *(const float4*)&scsh[co0];
            const float4 h4 = *(const float4*)&scsh[COUT + co0];
            const float sc[4] = {s4.x, s4.y, s4.z, s4.w};
            const float sh[4] = {h4.x, h4.y, h4.z, h4.w};

            float ps[4] = {0.f, 0.f, 0.f, 0.f};
#pragma unroll
            for (int mt = 0; mt < 4; ++mt) {
                const int l = wl * 64 + mt * 16 + lan15;
                const size_t gi = (bL + l0 + l) * COUT + co0;
                _Float16 a4[4];
                *(int2*)a4 = *(const int2*)(aux + gi);
#pragma unroll
                for (int r = 0; r < 4; ++r)
                    ps[r] += silu_f(fmaf(acc[mt][nt][r], sc[r], sh[r]) + (float)a4[r]);
            }
#pragma unroll
            for (int r = 0; r < 4; ++r) {
                ps[r] += __shfl_xor(ps[r], 1, 64);
                ps[r] += __shfl_xor(ps[r], 2, 64);
                ps[r] += __shfl_xor(ps[r], 4, 64);
                ps[r] += __shfl_xor(ps[r], 8, 64);
            }
            if (lan15 == 0) {
#pragma unroll
                for (int r = 0; r < 4; ++r)
                    pf[wl][co0 + r] = ps[r];
            }
        }
        __syncthreads();
        if (tid < COUT)
            atomicAdd(&gsum[b * COUT + tid], pf[0][tid] + pf[1][tid]);
    } else {
        // z -> LDS (b64 scatter) -> coalesced sweep (R10/R12-proven, WRITE ~1x)
        __syncthreads();   // all staging reads done before smem reuse
        _Float16* zl = (_Float16*)smem;
#pragma unroll
        for (int nt = 0; nt < NT; ++nt) {
            const int co0 = (wc * NT + nt) * 16 + (lane >> 4) * 4;
            const float4 s4 = *(const float4*)&scsh[co0];
            const float4 h4 = *(const float4*)&scsh[COUT + co0];
            const float sc[4] = {s4.x, s4.y, s4.z, s4.w};
            const float sh[4] = {h4.x, h4.y, h4.z, h4.w};
#pragma unroll
            for (int mt = 0; mt < 4; ++mt) {
                const int l_loc = wl * 64 + mt * 16 + lan15;
                __align__(8) _Float16 o4[4];
#pragma unroll
                for (int r = 0; r < 4; ++r)
                    o4[r] = (_Float16)fmaf(acc[mt][nt][r], sc[r], sh[r]);
                *(int2*)&zl[l_loc * ESTR + co0] = *(const int2*)o4;
            }
        }
        __syncthreads();

        constexpr int CO8 = COUT / 8;
        constexpr int LG  = (CO8 == 16) ? 4 : (CO8 == 8) ? 3 : 2;
        constexpr int RPI = 64 / CO8;
        const int co = (lane & (CO8 - 1)) * 8;

#pragma unroll
        for (int s2 = 0; s2 < CO8 / 2; ++s2) {
            const int l = w * 32 + s2 * RPI + (lane >> LG);
            _Float16 z8[8];
            *(int4*)z8 = *(const int4*)&zl[l * ESTR + co];
            const size_t gidx = (bL + l0 + l) * COUT + co;
            __align__(16) _Float16 o8[8];
            if constexpr (MODE == 0) {
#pragma unroll
                for (int j = 0; j < 8; ++j) o8[j] = (_Float16)silu_f((float)z8[j]);
            } else {
                _Float16 g8[8];
                *(int4*)g8 = *(const int4*)(aux + gidx);
#pragma unroll
                for (int j = 0; j < 8; ++j) o8[j] = (_Float16)((float)g8[j] * sigm_f((float)z8[j]));
            }
            *(int4*)(out + gidx) = *(const int4*)o8;
        }
    }
}

// ============================================================================
// 4-qubit statevector circuit helpers
// ============================================================================
template <int BW> DEV void g_ry(float (&re)[16], float (&im)[16], float t) {
    float s, c; sincosf(0.5f * t, &s, &c);
#pragma unroll
    for (int i = 0; i < 16; ++i)
        if (!(i & BW)) {
            const int j = i | BW;
            float r0 = re[i], q0 = im[i], r1 = re[j], q1 = im[j];
            re[i] = c * r0 - s * r1; im[i] = c * q0 - s * q1;
            re[j] = s * r0 + c * r1; im[j] = s * q0 + c * q1;
        }
}
template <int BW> DEV void g_rz(float (&re)[16], float (&im)[16], float t) {
    float s, c; sincosf(0.5f * t, &s, &c);
#pragma unroll
    for (int i = 0; i < 16; ++i) {
        float r = re[i], q = im[i];
        if (i & BW) { re[i] = r * c - q * s; im[i] = q * c + r * s; }
        else        { re[i] = r * c + q * s; im[i] = q * c - r * s; }
    }
}
template <int BC, int BT> DEV void g_cnot(float (&re)[16], float (&im)[16]) {
#pragma unroll
    for (int i = 0; i < 16; ++i)
        if ((i & BC) && !(i & BT)) {
            const int j = i | BT;
            float r = re[i]; re[i] = re[j]; re[j] = r;
            float q = im[i]; im[i] = im[j]; im[j] = q;
        }
}

// ============================================================================
// merged quantum + FC head: one block (64 thr) per batch row
// ============================================================================
__global__ __launch_bounds__(64) void qhead_k(
    const float* __restrict__ gsum, const float* __restrict__ Wfm,
    const float* __restrict__ bfm, const float* __restrict__ qw,
    const float* __restrict__ Wf1, const float* __restrict__ bf1, const float* __restrict__ bnf1,
    const float* __restrict__ Wf2, const float* __restrict__ bf2, const float* __restrict__ bnf2,
    const float* __restrict__ Wf3, const float* __restrict__ bf3,
    float* __restrict__ out)
{
    const int b = blockIdx.x, t = threadIdx.x;
    const float inv = 1.f / (float)L_LEN;

    float part[4];
    {
        const float gv0 = gsum[b * 128 + t] * inv;
        const float gv1 = gsum[b * 128 + 64 + t] * inv;
#pragma unroll
        for (int j = 0; j < 4; ++j)
            part[j] = gv0 * Wfm[j * 128 + t] + gv1 * Wfm[j * 128 + 64 + t];
    }
#pragma unroll
    for (int j = 0; j < 4; ++j) {
#pragma unroll
        for (int m = 1; m < 64; m <<= 1)
            part[j] += __shfl_xor(part[j], m, 64);
        part[j] += bfm[j];
    }

    float re[16], im[16];
#pragma unroll
    for (int i = 0; i < 16; ++i) { re[i] = 0.f; im[i] = 0.f; }
    re[0] = 1.f;
    g_ry<8>(re, im, part[0]); g_ry<4>(re, im, part[1]); g_ry<2>(re, im, part[2]); g_ry<1>(re, im, part[3]);
    g_rz<8>(re, im, qw[0]);  g_ry<8>(re, im, qw[1]);
    g_rz<4>(re, im, qw[2]);  g_ry<4>(re, im, qw[3]);
    g_rz<2>(re, im, qw[4]);  g_ry<2>(re, im, qw[5]);
    g_rz<1>(re, im, qw[6]);  g_ry<1>(re, im, qw[7]);
    g_cnot<8, 4>(re, im); g_cnot<4, 2>(re, im); g_cnot<2, 1>(re, im);
    g_rz<8>(re, im, qw[8]);  g_ry<8>(re, im, qw[9]);
    g_rz<4>(re, im, qw[10]); g_ry<4>(re, im, qw[11]);
    g_rz<2>(re, im, qw[12]); g_ry<2>(re, im, qw[13]);
    g_rz<1>(re, im, qw[14]); g_ry<1>(re, im, qw[15]);

    float pr[16];
#pragma unroll
    for (int i = 0; i < 16; ++i) pr[i] = re[i] * re[i] + im[i] * im[i];
    float q[4];
#pragma unroll
    for (int w = 0; w < 4; ++w) {
        const int bw = 8 >> w;
        float e = 0.f;
#pragma unroll
        for (int i = 0; i < 16; ++i) e += (i & bw) ? -pr[i] : pr[i];
        q[w] = e;
    }

    __shared__ float x1[64], x2[32];
    {
        float a = bf1[t];
#pragma unroll
        for (int k = 0; k < 4; ++k) a = fmaf(q[k], Wf1[t * 4 + k], a);
        const float sc = bnf1[t] / sqrtf(bnf1[192 + t] + 1e-5f);
        const float z  = (a - bnf1[128 + t]) * sc + bnf1[64 + t];
        x1[t] = silu_f(z);
    }
    __syncthreads();
    if (t < 32) {
        float a = bf2[t];
        for (int k = 0; k < 64; ++k) a = fmaf(x1[k], Wf2[t * 64 + k], a);
        const float sc = bnf2[t] / sqrtf(bnf2[96 + t] + 1e-5f);
        const float z  = (a - bnf2[64 + t]) * sc + bnf2[32 + t];
        x2[t] = silu_f(z);
    }
    __syncthreads();
    if (t == 0) {
        float a = bf3[0];
        for (int k = 0; k < 32; ++k) a = fmaf(x2[k], Wf3[k], a);
        out[b] = a;
    }
}

// ============================================================================
extern "C" void kernel_launch(void* const* d_in, const int* in_sizes, int n_in,
                              void* d_out, int out_size, void* d_ws, size_t ws_size,
                              hipStream_t stream)
{
    (void)n_in; (void)out_size;
    const float* x    = (const float*)d_in[0];
    const float* W1   = (const float*)d_in[1];
    const float* b1   = (const float*)d_in[2];
    const float* bn1  = (const float*)d_in[3];
    const float* Wa1  = (const float*)d_in[4];
    const float* ba1  = (const float*)d_in[5];
    const float* bna1 = (const float*)d_in[6];
    const float* Wa2  = (const float*)d_in[7];
    const float* ba2  = (const float*)d_in[8];
    const float* bna2 = (const float*)d_in[9];
    const float* Wd1  = (const float*)d_in[10];
    const float* bdd1 = (const float*)d_in[11];
    const float* bnd1 = (const float*)d_in[12];
    const float* Wd2  = (const float*)d_in[13];
    const float* bdd2 = (const float*)d_in[14];
    const float* bnd2 = (const float*)d_in[15];
    const float* Wr1  = (const float*)d_in[16];
    const float* br1  = (const float*)d_in[17];
    const float* bnr1 = (const float*)d_in[18];
    const float* Wr2  = (const float*)d_in[19];
    const float* br2  = (const float*)d_in[20];
    const float* bnr2 = (const float*)d_in[21];
    const float* Wfm  = (const float*)d_in[22];
    const float* bfm  = (const float*)d_in[23];
    const float* qw   = (const float*)d_in[24];
    const float* Wf1  = (const float*)d_in[25];
    const float* bf1  = (const float*)d_in[26];
    const float* bnf1 = (const float*)d_in[27];
    const float* Wf2  = (const float*)d_in[28];
    const float* bf2  = (const float*)d_in[29];
    const float* bnf2 = (const float*)d_in[30];
    const float* Wf3  = (const float*)d_in[31];
    const float* bf3  = (const float*)d_in[32];

    const int B = in_sizes[0] / L_LEN;  // 128

    char* base = (char*)d_ws;
    size_t off = 0;
    auto alloc = [&](size_t bytes) -> char* {
        off = (off + 255) & ~(size_t)255;
        char* p = base + off;
        off += bytes;
        return p;
    };

    float* gbuf  = (float*)alloc((size_t)B * 128 * 4);
    float* zpage = (float*)alloc(256);

    auto wfrag = [&](int cin, int cout, int k) -> _Float16* {
        return (_Float16*)alloc((size_t)k * cout * cin * 2);   // single plane
    };
    _Float16* wa1f = wfrag(64, 32, 7);
    _Float16* wa2f = wfrag(32, 64, 7);
    _Float16* wd1f = wfrag(64, 128, 3);
    _Float16* wd2f = wfrag(128, 128, 3);
    _Float16* wr1f = wfrag(128, 128, 3);
    _Float16* wr2f = wfrag(128, 128, 3);

    // pre-folded BN (sc|sh) per conv layer
    auto scshb = [&](int cout) -> float* { return (float*)alloc((size_t)cout * 2 * 4); };
    float* sA1 = scshb(32);
    float* sA2 = scshb(64);
    float* sD1 = scshb(128);
    float* sD2 = scshb(128);
    float* sR1 = scshb(128);
    float* sR2 = scshb(128);

    // ---- activation buffers with lifetime-aliasing ----
    const size_t fixed = (off + 255) & ~(size_t)255;
    const size_t PS = (size_t)2 * L_LEN * 256;
    size_t avail = (ws_size > fixed + 4096) ? ws_size - fixed - 4096 : 0;
    int chunk = B;
    while (chunk > 1 && (size_t)chunk * PS > avail) chunk >>= 1;

    auto aplane = [&](int C, int c) -> _Float16* {
        return (_Float16*)alloc((size_t)c * L_LEN * C * 2);
    };
    _Float16* h0 = aplane(64,  chunk);   // region A
    _Float16* a1 = aplane(32,  chunk);   // region B
    (void)     aplane(32,  chunk);       // region E (spacer for d2 overlap)
    _Float16* d1 = aplane(128, chunk);   // region C (also r1)
    _Float16* d2 = h0;                   // d2 aliases A∪B∪E
    _Float16* r1 = d1;

    // ---- merged weight prep ----
    PrepArgs pa;
    pa.W[0] = Wa1; pa.wf[0] = wa1f; pa.cin[0] = 64;  pa.cout[0] = 32;  pa.kk[0] = 7;
    pa.W[1] = Wa2; pa.wf[1] = wa2f; pa.cin[1] = 32;  pa.cout[1] = 64;  pa.kk[1] = 7;
    pa.W[2] = Wd1; pa.wf[2] = wd1f; pa.cin[2] = 64;  pa.cout[2] = 128; pa.kk[2] = 3;
    pa.W[3] = Wd2; pa.wf[3] = wd2f; pa.cin[3] = 128; pa.cout[3] = 128; pa.kk[3] = 3;
    pa.W[4] = Wr1; pa.wf[4] = wr1f; pa.cin[4] = 128; pa.cout[4] = 128; pa.kk[4] = 3;
    pa.W[5] = Wr2; pa.wf[5] = wr2f; pa.cin[5] = 128; pa.cout[5] = 128; pa.kk[5] = 3;
    pa.cum[0] = 0;
    for (int i = 0; i < 6; ++i)
        pa.cum[i + 1] = pa.cum[i] + (pa.cin[i] / 32) * pa.kk[i] * (pa.cout[i] / 16) * 64;
    prep_all_k<<<dim3((pa.cum[6] + 255) / 256), dim3(256), 0, stream>>>(pa);

    BnArgs ba;
    ba.bias[0] = ba1;  ba.bnp[0] = bna1; ba.scsh[0] = sA1; ba.cout[0] = 32;
    ba.bias[1] = ba2;  ba.bnp[1] = bna2; ba.scsh[1] = sA2; ba.cout[1] = 64;
    ba.bias[2] = bdd1; ba.bnp[2] = bnd1; ba.scsh[2] = sD1; ba.cout[2] = 128;
    ba.bias[3] = bdd2; ba.bnp[3] = bnd2; ba.scsh[3] = sD2; ba.cout[3] = 128;
    ba.bias[4] = br1;  ba.bnp[4] = bnr1; ba.scsh[4] = sR1; ba.cout[4] = 128;
    ba.bias[5] = br2;  ba.bnp[5] = bnr2; ba.scsh[5] = sR2; ba.cout[5] = 128;
    ba.cum[0] = 0;
    for (int i = 0; i < 6; ++i) ba.cum[i + 1] = ba.cum[i] + ba.cout[i];
    bn_prep_k<<<dim3((ba.cum[6] + 255) / 256), dim3(256), 0, stream>>>(ba);

    hipMemsetAsync(gbuf, 0, (size_t)B * 128 * sizeof(float), stream);
    hipMemsetAsync(zpage, 0, 256, stream);

    const dim3 blk(256);
    for (int sft = 0; sft < B; sft += chunk) {
        const int c = (chunk < B - sft) ? chunk : (B - sft);
        const dim3 cg(L_LEN / 128, 1, c);
        conv1_k<<<dim3(64, c), blk, 0, stream>>>(x + (size_t)sft * L_LEN, W1, b1, bn1, h0);
        conv_mfma_k<64, 32, 7, 1, 0><<<cg, blk, 0, stream>>>(h0, wa1f, sA1, nullptr, a1, nullptr, zpage);
        conv_mfma_k<32, 64, 7, 1, 1><<<cg, blk, 0, stream>>>(a1, wa2f, sA2, h0, h0, nullptr, zpage);
        conv_mfma_k<64, 128, 3, 2, 0><<<cg, blk, 0, stream>>>(h0, wd1f, sD1, nullptr, d1, nullptr, zpage);
        conv_mfma_k<128, 128, 3, 4, 0><<<cg, blk, 0, stream>>>(d1, wd2f, sD2, nullptr, d2, nullptr, zpage);
        conv_mfma_k<128, 128, 3, 1, 0><<<cg, blk, 0, stream>>>(d2, wr1f, sR1, nullptr, r1, nullptr, zpage);
        conv_mfma_k<128, 128, 3, 1, 3><<<cg, blk, 0, stream>>>(r1, wr2f, sR2, d2, nullptr, gbuf + (size_t)sft * 128, zpage);
    }

    qhead_k<<<dim3(B), dim3(64), 0, stream>>>(gbuf, Wfm, bfm, qw,
                                              Wf1, bf1, bnf1, Wf2, bf2, bnf2, Wf3, bf3,
                                              (float*)d_out);
}